// Round 12
// baseline (4937.423 us; speedup 1.0000x reference)
//
#include <hip/hip_runtime.h>
#include <math.h>

static constexpr int V  = 1024;
static constexpr int NH = 256;
static constexpr int B  = 128;
static constexpr int T  = 512;
static constexpr size_t BV  = (size_t)B * V;
static constexpr size_t YSZ = (size_t)T * B * V;   // 67,108,864
static constexpr unsigned SENT = 0xFFC0DEADu;      // NaN payload; h in (-1,1) never equals it

typedef _Float16 h8 __attribute__((ext_vector_type(8)));
typedef _Float16 h4 __attribute__((ext_vector_type(4)));
typedef float f32x4 __attribute__((ext_vector_type(4)));

#define MFMA16(a, b, c) __builtin_amdgcn_mfma_f32_16x16x32_f16((a), (b), (c), 0, 0, 0)
#define MALL_LD(dst, src) asm volatile("global_load_dwordx4 %0, %1, off sc0 sc1" : "=v"(dst) : "v"(src))

__device__ __forceinline__ void mall_store(float* p, f32x4 v) {
    asm volatile("global_store_dwordx4 %0, %1, off sc0 sc1" :: "v"(p), "v"(v) : "memory");
}

__device__ __forceinline__ float fast_sigmoid(float x) {
    float a = fminf(-1.442695041f * x, 126.0f);
    return __builtin_amdgcn_rcpf(1.0f + __builtin_amdgcn_exp2f(a));
}

__device__ __forceinline__ int has_sent(f32x4 v) {
    return (__float_as_uint(v[0]) == SENT) | (__float_as_uint(v[1]) == SENT) |
           (__float_as_uint(v[2]) == SENT) | (__float_as_uint(v[3]) == SENT);
}

__device__ __forceinline__ void cvtv(f32x4 u, h4* hi4, h4* lo4) {
    h4 hi, lo;
    #pragma unroll
    for (int e = 0; e < 4; ++e) {
        _Float16 h = (_Float16)u[e];
        hi[e] = h; lo[e] = (_Float16)((u[e] - (float)h) * 2048.0f);
    }
    *hi4 = hi; *lo4 = lo;
}

__device__ __forceinline__ float sel4(f32x4 p, int i) {
    float r = p[0];
    r = (i == 1) ? p[1] : r;
    r = (i == 2) ? p[2] : r;
    r = (i == 3) ? p[3] : r;
    return r;
}
__device__ __forceinline__ float pick4(float a0, float a1, float a2, float a3, int i) {
    float r = a0;
    r = (i == 1) ? a1 : r;
    r = (i == 2) ? a2 : r;
    r = (i == 3) ? a3 : r;
    return r;
}

// Split-f16: x = hi + lo*2^-11, lo pre-scaled 2048. Dot = hi*hi + (hi*lo + lo*hi)*2^-11.
// d_out: y[T*B][V], tails H1,C1,H2,C2. Stash: h2(t)->y[t][0:256], h1(t)->y[t][256:512].
// Sync = data-as-flag (SENT) via 16B MALL (sc0 sc1) ops.
// k_persist: 128 blocks x 512 thr; block (mp=bid>>4, np=bid&15) owns rows mp*16..+16,
// hidden cols np*16..+16 of BOTH cells. Waves 0-3 COMPUTE (16 gate-cols, full K,
// in-wave shuffle-transpose combine); waves 4-7 STAGE next-iter h into the other
// LDS buffer (MALL latency hidden under compute). ONE barrier per step.

__global__ __launch_bounds__(256) void k_prep(
    const float* __restrict__ W1f, const float* __restrict__ W1i,
    const float* __restrict__ W1o, const float* __restrict__ W1c,
    const float* __restrict__ W2f, const float* __restrict__ W2i,
    const float* __restrict__ W2o, const float* __restrict__ W2c,
    const float* __restrict__ Wout,
    const float* __restrict__ b1f, const float* __restrict__ b1i,
    const float* __restrict__ b1o, const float* __restrict__ b1c,
    const float* __restrict__ b2f, const float* __restrict__ b2i,
    const float* __restrict__ b2o, const float* __restrict__ b2c,
    _Float16* __restrict__ pk2, _Float16* __restrict__ pk1,
    _Float16* __restrict__ pkY, float* __restrict__ bp2, float* __restrict__ bp1)
{
    int idx = blockIdx.x * 256 + threadIdx.x;
    if (idx < 2097152) {
        int KB, e, rowoff = 0;
        bool vocabN = false;
        _Float16* dst;
        if (idx < 1048576)      { e = idx;            KB = 16; dst = pk2; }
        else if (idx < 1572864) { e = idx - 1048576;  KB = 8;  dst = pk1; rowoff = V; }
        else                    { e = idx - 1572864;  KB = 8;  dst = pkY; vocabN = true; }
        int S = 64 * KB * 512;
        int split = e / S, r = e % S;
        int grp = r / (KB * 512);
        int r2  = r % (KB * 512);
        int kb = r2 >> 9, lane = (r2 >> 3) & 63, i = r2 & 7;
        int n = grp * 16 + (lane & 15);
        int k = kb * 32 + (lane >> 4) * 8 + i;
        float val;
        if (vocabN) {
            val = Wout[(size_t)k * 1024 + n];
        } else {
            int j = n >> 2, g = n & 3;
            const float* W = (KB == 16)
                ? (g == 0 ? W2f : g == 1 ? W2i : g == 2 ? W2o : W2c)
                : (g == 0 ? W1f : g == 1 ? W1i : g == 2 ? W1o : W1c);
            val = W[(size_t)(rowoff + k) * NH + j];
        }
        _Float16 hi = (_Float16)val;
        dst[e] = split ? (_Float16)((val - (float)hi) * 2048.0f) : hi;
    } else {
        int bi = idx - 2097152;
        if (bi < 1024) {
            int j = bi >> 2, g = bi & 3;
            bp2[bi] = (g == 0 ? b2f : g == 1 ? b2i : g == 2 ? b2o : b2c)[j];
        } else if (bi < 2048) {
            int b2_ = bi - 1024;
            int j = b2_ >> 2, g = b2_ & 3;
            bp1[b2_] = (g == 0 ? b1f : g == 1 ? b1i : g == 2 ? b1o : b1c)[j];
        }
    }
}

__global__ __launch_bounds__(256) void k_sent(float* __restrict__ y) {
    const float s = __uint_as_float(SENT);
    const f32x4 sv = {s, s, s, s};
    int gid = blockIdx.x * 256 + threadIdx.x;       // 524288 threads
    for (int n = gid; n < 8388608; n += 524288) {
        int row = n >> 7, c4 = n & 127;
        *(f32x4*)&y[(size_t)row * V + c4 * 4] = sv;
    }
}

__global__ __launch_bounds__(512, 1) void k_persist(
    const int* __restrict__ X,
    const float* __restrict__ H1in, const float* __restrict__ C1in,
    const float* __restrict__ H2in, const float* __restrict__ C2in,
    float* __restrict__ y,
    float* __restrict__ H1t, float* __restrict__ C1t,
    float* __restrict__ H2t, float* __restrict__ C2t,
    const _Float16* __restrict__ pk2, const _Float16* __restrict__ pk1,
    const float* __restrict__ bp2, const float* __restrict__ bp1,
    const float* __restrict__ W1f, const float* __restrict__ W1i,
    const float* __restrict__ W1o, const float* __restrict__ W1c)
{
    const int bid = blockIdx.x, tid = threadIdx.x;
    const int mp = bid >> 4, np = bid & 15, r0 = mp * 16;

    __shared__ _Float16 Ah[2][16][520];
    __shared__ _Float16 Al[2][16][520];

    const int wv = tid >> 6, lane = tid & 63;

    if (wv < 4) {
        // ===================== COMPUTE waves =====================
        const int wq = wv;
        const int col = lane & 15, kg = lane >> 4;
        const int c3 = lane & 3;
        const int orow = ((lane >> 4) << 2) | c3;
        const int jq = (lane >> 2) & 3;
        const int jglob = np * 16 + wq * 4 + jq;
        const int brow = r0 + orow;

        h8 wh1[8], wl1[8], wh2[16], wl2[16];
        {
            const _Float16* pB1 = pk1 + ((size_t)((np * 4 + wq) * 8) * 64 + lane) * 8;
            #pragma unroll
            for (int kb = 0; kb < 8; ++kb) {
                wh1[kb] = *(const h8*)(pB1 + (size_t)kb * 512);
                wl1[kb] = *(const h8*)(pB1 + 262144 + (size_t)kb * 512);
            }
            const _Float16* pB2 = pk2 + ((size_t)((np * 4 + wq) * 16) * 64 + lane) * 8;
            #pragma unroll
            for (int kb = 0; kb < 16; ++kb) {
                wh2[kb] = *(const h8*)(pB2 + (size_t)kb * 512);
                wl2[kb] = *(const h8*)(pB2 + 524288 + (size_t)kb * 512);
            }
        }
        float creg1 = C1in[brow * NH + jglob];
        float creg2 = C2in[brow * NH + jglob];
        const f32x4 bb1 = *(const f32x4*)&bp1[(np * 16 + wq * 4 + jq) * 4];
        const f32x4 bb2 = *(const f32x4*)&bp2[(np * 16 + wq * 4 + jq) * 4];
        float* const hst1base = y + (size_t)brow * V + 256 + np * 16 + wq * 4;
        float* const hst2base = y + (size_t)brow * V + np * 16 + wq * 4;

        __syncthreads();   // B0: stagers put H1in->buf1.h1, H2in->buf0.h2

        // ---- prologue: cell1(0) from buf[1].h1, store h1(0) ----
        {
            int tok = X[brow * T + 0];
            float w1f_ = W1f[(size_t)tok * NH + jglob];
            float w1i_ = W1i[(size_t)tok * NH + jglob];
            float w1o_ = W1o[(size_t)tok * NH + jglob];
            float w1c_ = W1c[(size_t)tok * NH + jglob];
            f32x4 a0 = {0.f, 0.f, 0.f, 0.f}, a1 = a0, a2 = a0;
            #pragma unroll
            for (int kb = 0; kb < 8; ++kb) {
                h8 ah = *(const h8*)&Ah[1][col][kb * 32 + kg * 8];
                h8 al = *(const h8*)&Al[1][col][kb * 32 + kg * 8];
                a0 = MFMA16(ah, wh1[kb], a0);
                a1 = MFMA16(ah, wl1[kb], a1);
                a2 = MFMA16(al, wh1[kb], a2);
            }
            f32x4 comb = a0 + (a1 + a2) * (1.0f / 2048.0f);
            float s0 = sel4(comb, c3);
            float s1 = __shfl_xor(sel4(comb, c3 ^ 1), 1);
            float s2 = __shfl_xor(sel4(comb, c3 ^ 2), 2);
            float s3 = __shfl_xor(sel4(comb, c3 ^ 3), 3);
            float pf = pick4(s0, s1, s2, s3, c3)     + bb1[0] + w1f_;
            float pi = pick4(s0, s1, s2, s3, c3 ^ 1) + bb1[1] + w1i_;
            float po = pick4(s0, s1, s2, s3, c3 ^ 2) + bb1[2] + w1o_;
            float pc = pick4(s0, s1, s2, s3, c3 ^ 3) + bb1[3] + w1c_;
            float fg = fast_sigmoid(pf), ig = fast_sigmoid(pi), og = fast_sigmoid(po);
            creg1 = fmaf(fg, creg1, ig * tanhf(pc));
            float h = og * tanhf(creg1);
            float g1 = __shfl(h, (lane & 51) | 4);
            float g2 = __shfl(h, (lane & 51) | 8);
            float g3 = __shfl(h, (lane & 51) | 12);
            if ((lane & 12) == 0) {
                f32x4 hv = {h, g1, g2, g3};
                mall_store(hst1base, hv);   // y[0][brow][256+..]
            }
        }
        __syncthreads();   // B1: buf[0] = {h1(0), H2in} ready

        // ---- main loop ----
        for (int t = 0; t < T; ++t) {
            const int tb = t & 1;
            // cell1(t+1)
            if (t <= 510) {
                int tok = X[brow * T + t + 1];
                float w1f_ = W1f[(size_t)tok * NH + jglob];
                float w1i_ = W1i[(size_t)tok * NH + jglob];
                float w1o_ = W1o[(size_t)tok * NH + jglob];
                float w1c_ = W1c[(size_t)tok * NH + jglob];
                f32x4 a0 = {0.f, 0.f, 0.f, 0.f}, a1 = a0, a2 = a0;
                #pragma unroll
                for (int kb = 0; kb < 8; ++kb) {
                    h8 ah = *(const h8*)&Ah[tb][col][kb * 32 + kg * 8];
                    h8 al = *(const h8*)&Al[tb][col][kb * 32 + kg * 8];
                    a0 = MFMA16(ah, wh1[kb], a0);
                    a1 = MFMA16(ah, wl1[kb], a1);
                    a2 = MFMA16(al, wh1[kb], a2);
                }
                f32x4 comb = a0 + (a1 + a2) * (1.0f / 2048.0f);
                float s0 = sel4(comb, c3);
                float s1 = __shfl_xor(sel4(comb, c3 ^ 1), 1);
                float s2 = __shfl_xor(sel4(comb, c3 ^ 2), 2);
                float s3 = __shfl_xor(sel4(comb, c3 ^ 3), 3);
                float pf = pick4(s0, s1, s2, s3, c3)     + bb1[0] + w1f_;
                float pi = pick4(s0, s1, s2, s3, c3 ^ 1) + bb1[1] + w1i_;
                float po = pick4(s0, s1, s2, s3, c3 ^ 2) + bb1[2] + w1o_;
                float pc = pick4(s0, s1, s2, s3, c3 ^ 3) + bb1[3] + w1c_;
                float fg = fast_sigmoid(pf), ig = fast_sigmoid(pi), og = fast_sigmoid(po);
                creg1 = fmaf(fg, creg1, ig * tanhf(pc));
                float h = og * tanhf(creg1);
                float g1 = __shfl(h, (lane & 51) | 4);
                float g2 = __shfl(h, (lane & 51) | 8);
                float g3 = __shfl(h, (lane & 51) | 12);
                if ((lane & 12) == 0) {
                    f32x4 hv = {h, g1, g2, g3};
                    mall_store(hst1base + (size_t)(t + 1) * BV, hv);
                }
                if (t == 510) { H1t[brow * NH + jglob] = h; C1t[brow * NH + jglob] = creg1; }
            }
            // cell2(t)
            {
                f32x4 a0 = {0.f, 0.f, 0.f, 0.f}, a1 = a0, a2 = a0;
                #pragma unroll
                for (int kb = 0; kb < 16; ++kb) {
                    h8 ah = *(const h8*)&Ah[tb][col][kb * 32 + kg * 8];
                    h8 al = *(const h8*)&Al[tb][col][kb * 32 + kg * 8];
                    a0 = MFMA16(ah, wh2[kb], a0);
                    a1 = MFMA16(ah, wl2[kb], a1);
                    a2 = MFMA16(al, wh2[kb], a2);
                }
                f32x4 comb = a0 + (a1 + a2) * (1.0f / 2048.0f);
                float s0 = sel4(comb, c3);
                float s1 = __shfl_xor(sel4(comb, c3 ^ 1), 1);
                float s2 = __shfl_xor(sel4(comb, c3 ^ 2), 2);
                float s3 = __shfl_xor(sel4(comb, c3 ^ 3), 3);
                float pf = pick4(s0, s1, s2, s3, c3)     + bb2[0];
                float pi = pick4(s0, s1, s2, s3, c3 ^ 1) + bb2[1];
                float po = pick4(s0, s1, s2, s3, c3 ^ 2) + bb2[2];
                float pc = pick4(s0, s1, s2, s3, c3 ^ 3) + bb2[3];
                float fg = fast_sigmoid(pf), ig = fast_sigmoid(pi), og = fast_sigmoid(po);
                creg2 = fmaf(fg, creg2, ig * tanhf(pc));
                float h = og * tanhf(creg2);
                float g1 = __shfl(h, (lane & 51) | 4);
                float g2 = __shfl(h, (lane & 51) | 8);
                float g3 = __shfl(h, (lane & 51) | 12);
                if ((lane & 12) == 0) {
                    f32x4 hv = {h, g1, g2, g3};
                    mall_store(hst2base + (size_t)t * BV, hv);
                }
                if (t == 511) { H2t[brow * NH + jglob] = h; C2t[brow * NH + jglob] = creg2; }
            }
            __syncthreads();   // end of iter: buf[(t+1)&1] staged by stagers
        }
    } else {
        // ===================== STAGER waves =====================
        const int st = tid & 255;
        const int sk4 = st & 63;       // col4 in 0..63 -> cols sk4*4 of each 256-half
        const int srb = st >> 6;       // rows srb, srb+4, srb+8, srb+12

        // prologue: H1in -> buf[1].h1 ; H2in -> buf[0].h2
        #pragma unroll
        for (int k = 0; k < 4; ++k) {
            const int row = srb + k * 4;
            f32x4 u1 = *(const f32x4*)(H1in + (size_t)(r0 + row) * NH + sk4 * 4);
            cvtv(u1, (h4*)&Ah[1][row][sk4 * 4], (h4*)&Al[1][row][sk4 * 4]);
            f32x4 u2 = *(const f32x4*)(H2in + (size_t)(r0 + row) * NH + sk4 * 4);
            cvtv(u2, (h4*)&Ah[0][row][256 + sk4 * 4], (h4*)&Al[0][row][256 + sk4 * 4]);
        }
        __syncthreads();   // B0

        // poll h1(0) -> buf[0].h1  (produced by computers during this phase)
        {
            f32x4 ua, ub, uc, ud;
            const float* pa = y + (size_t)(r0 + srb)      * V + 256 + sk4 * 4;
            const float* pb = y + (size_t)(r0 + srb + 4)  * V + 256 + sk4 * 4;
            const float* pc_ = y + (size_t)(r0 + srb + 8) * V + 256 + sk4 * 4;
            const float* pd = y + (size_t)(r0 + srb + 12) * V + 256 + sk4 * 4;
            MALL_LD(ua, pa); MALL_LD(ub, pb); MALL_LD(uc, pc_); MALL_LD(ud, pd);
            asm volatile("s_waitcnt vmcnt(0)" : "+v"(ua), "+v"(ub), "+v"(uc), "+v"(ud));
            while (__any(has_sent(ua) | has_sent(ub) | has_sent(uc) | has_sent(ud))) {
                __builtin_amdgcn_s_sleep(1);
                MALL_LD(ua, pa); MALL_LD(ub, pb); MALL_LD(uc, pc_); MALL_LD(ud, pd);
                asm volatile("s_waitcnt vmcnt(0)" : "+v"(ua), "+v"(ub), "+v"(uc), "+v"(ud));
            }
            cvtv(ua, (h4*)&Ah[0][srb][sk4 * 4],      (h4*)&Al[0][srb][sk4 * 4]);
            cvtv(ub, (h4*)&Ah[0][srb + 4][sk4 * 4],  (h4*)&Al[0][srb + 4][sk4 * 4]);
            cvtv(uc, (h4*)&Ah[0][srb + 8][sk4 * 4],  (h4*)&Al[0][srb + 8][sk4 * 4]);
            cvtv(ud, (h4*)&Ah[0][srb + 12][sk4 * 4], (h4*)&Al[0][srb + 12][sk4 * 4]);
        }
        __syncthreads();   // B1

        for (int t = 0; t < T; ++t) {
            if (t <= 510) {
                const int tb1 = (t + 1) & 1;
                // h1(t+1) -> buf[tb1].h1 ; h2(t) -> buf[tb1].h2
                f32x4 a0, a1_, a2_, a3_, b0, b1_, b2_, b3_;
                const float* q1a = y + (size_t)(t + 1) * BV + (size_t)(r0 + srb)      * V + 256 + sk4 * 4;
                const float* q1b = y + (size_t)(t + 1) * BV + (size_t)(r0 + srb + 4)  * V + 256 + sk4 * 4;
                const float* q1c = y + (size_t)(t + 1) * BV + (size_t)(r0 + srb + 8)  * V + 256 + sk4 * 4;
                const float* q1d = y + (size_t)(t + 1) * BV + (size_t)(r0 + srb + 12) * V + 256 + sk4 * 4;
                const float* q2a = y + (size_t)t * BV + (size_t)(r0 + srb)      * V + sk4 * 4;
                const float* q2b = y + (size_t)t * BV + (size_t)(r0 + srb + 4)  * V + sk4 * 4;
                const float* q2c = y + (size_t)t * BV + (size_t)(r0 + srb + 8)  * V + sk4 * 4;
                const float* q2d = y + (size_t)t * BV + (size_t)(r0 + srb + 12) * V + sk4 * 4;
                MALL_LD(a0, q1a); MALL_LD(a1_, q1b); MALL_LD(a2_, q1c); MALL_LD(a3_, q1d);
                MALL_LD(b0, q2a); MALL_LD(b1_, q2b); MALL_LD(b2_, q2c); MALL_LD(b3_, q2d);
                asm volatile("s_waitcnt vmcnt(0)"
                    : "+v"(a0), "+v"(a1_), "+v"(a2_), "+v"(a3_),
                      "+v"(b0), "+v"(b1_), "+v"(b2_), "+v"(b3_));
                while (__any(has_sent(a0) | has_sent(a1_) | has_sent(a2_) | has_sent(a3_) |
                             has_sent(b0) | has_sent(b1_) | has_sent(b2_) | has_sent(b3_))) {
                    __builtin_amdgcn_s_sleep(1);
                    MALL_LD(a0, q1a); MALL_LD(a1_, q1b); MALL_LD(a2_, q1c); MALL_LD(a3_, q1d);
                    MALL_LD(b0, q2a); MALL_LD(b1_, q2b); MALL_LD(b2_, q2c); MALL_LD(b3_, q2d);
                    asm volatile("s_waitcnt vmcnt(0)"
                        : "+v"(a0), "+v"(a1_), "+v"(a2_), "+v"(a3_),
                          "+v"(b0), "+v"(b1_), "+v"(b2_), "+v"(b3_));
                }
                cvtv(a0,  (h4*)&Ah[tb1][srb][sk4 * 4],       (h4*)&Al[tb1][srb][sk4 * 4]);
                cvtv(a1_, (h4*)&Ah[tb1][srb + 4][sk4 * 4],   (h4*)&Al[tb1][srb + 4][sk4 * 4]);
                cvtv(a2_, (h4*)&Ah[tb1][srb + 8][sk4 * 4],   (h4*)&Al[tb1][srb + 8][sk4 * 4]);
                cvtv(a3_, (h4*)&Ah[tb1][srb + 12][sk4 * 4],  (h4*)&Al[tb1][srb + 12][sk4 * 4]);
                cvtv(b0,  (h4*)&Ah[tb1][srb][256 + sk4 * 4],      (h4*)&Al[tb1][srb][256 + sk4 * 4]);
                cvtv(b1_, (h4*)&Ah[tb1][srb + 4][256 + sk4 * 4],  (h4*)&Al[tb1][srb + 4][256 + sk4 * 4]);
                cvtv(b2_, (h4*)&Ah[tb1][srb + 8][256 + sk4 * 4],  (h4*)&Al[tb1][srb + 8][256 + sk4 * 4]);
                cvtv(b3_, (h4*)&Ah[tb1][srb + 12][256 + sk4 * 4], (h4*)&Al[tb1][srb + 12][256 + sk4 * 4]);
            }
            __syncthreads();
        }
    }
}

// Y = H2_all @ Wout + bout, in place (block stages its 64 rows before writing).
__global__ __launch_bounds__(256) void k_ygemm2(
    float* __restrict__ y, const _Float16* __restrict__ pkY,
    const float* __restrict__ bout)
{
    __shared__ _Float16 Ah[64][264];
    __shared__ _Float16 Al[64][264];
    const size_t m0 = (size_t)blockIdx.x * 64;
    const int tid = threadIdx.x;
    for (int idx = tid; idx < 64 * 256; idx += 256) {
        int r = idx >> 8, k = idx & 255;
        float v = y[(m0 + r) * 1024 + k];
        _Float16 hi = (_Float16)v;
        Ah[r][k] = hi;
        Al[r][k] = (_Float16)((v - (float)hi) * 2048.0f);
    }
    __syncthreads();
    const int wave = tid >> 6, lane = tid & 63;
    const int col = lane & 15, kg = lane >> 4;
    const int ar = wave * 16 + col;
    const size_t orow = m0 + wave * 16 + kg * 4;
    for (int npass = 0; npass < 8; ++npass) {
        f32x4 aA[8], aB[8];
        #pragma unroll
        for (int nt = 0; nt < 8; ++nt) { aA[nt] = (f32x4){0.f,0.f,0.f,0.f}; aB[nt] = aA[nt]; }
        for (int kb = 0; kb < 8; ++kb) {
            h8 ah = *(const h8*)&Ah[ar][kb * 32 + kg * 8];
            h8 al = *(const h8*)&Al[ar][kb * 32 + kg * 8];
            #pragma unroll
            for (int nt = 0; nt < 8; ++nt) {
                const int ngrp = npass * 8 + nt;
                const _Float16* pb = pkY + ((size_t)(ngrp * 8 + kb) * 64 + lane) * 8;
                h8 bh = *(const h8*)pb;
                h8 bl = *(const h8*)(pb + 262144);
                aA[nt] = MFMA16(ah, bh, aA[nt]);
                aB[nt] = MFMA16(ah, bl, aB[nt]);
                aB[nt] = MFMA16(al, bh, aB[nt]);
            }
        }
        #pragma unroll
        for (int nt = 0; nt < 8; ++nt) {
            int n = npass * 128 + nt * 16 + col;
            float bbo = bout[n];
            #pragma unroll
            for (int q = 0; q < 4; ++q)
                y[(orow + q) * 1024 + n] = aA[nt][q] + aB[nt][q] * (1.0f / 2048.0f) + bbo;
        }
    }
}

// ---------------- launch ----------------
extern "C" void kernel_launch(void* const* d_in, const int* in_sizes, int n_in,
                              void* d_out, int out_size, void* d_ws, size_t ws_size,
                              hipStream_t stream) {
    const int*   X    = (const int*)  d_in[0];
    const float* H1in = (const float*)d_in[1];
    const float* C1in = (const float*)d_in[2];
    const float* H2in = (const float*)d_in[3];
    const float* C2in = (const float*)d_in[4];
    const float* W1f = (const float*)d_in[5];  const float* b1f = (const float*)d_in[6];
    const float* W1i = (const float*)d_in[7];  const float* b1i = (const float*)d_in[8];
    const float* W1o = (const float*)d_in[9];  const float* b1o = (const float*)d_in[10];
    const float* W1c = (const float*)d_in[11]; const float* b1c = (const float*)d_in[12];
    const float* W2f = (const float*)d_in[13]; const float* b2f = (const float*)d_in[14];
    const float* W2i = (const float*)d_in[15]; const float* b2i = (const float*)d_in[16];
    const float* W2o = (const float*)d_in[17]; const float* b2o = (const float*)d_in[18];
    const float* W2c = (const float*)d_in[19]; const float* b2c = (const float*)d_in[20];
    const float* Wout = (const float*)d_in[21]; const float* bout = (const float*)d_in[22];

    float* y   = (float*)d_out;
    float* H1t = y + YSZ;
    float* C1t = y + YSZ + 1 * 32768;
    float* H2t = y + YSZ + 2 * 32768;
    float* C2t = y + YSZ + 3 * 32768;

    char* ws = (char*)d_ws;
    _Float16* pk2 = (_Float16*)ws;
    _Float16* pk1 = pk2 + 1048576;
    _Float16* pkY = pk1 + 524288;
    float* bp2 = (float*)(ws + 4194304);
    float* bp1 = bp2 + 1024;

    k_prep<<<8200, 256, 0, stream>>>(W1f, W1i, W1o, W1c, W2f, W2i, W2o, W2c, Wout,
                                     b1f, b1i, b1o, b1c, b2f, b2i, b2o, b2c,
                                     pk2, pk1, pkY, bp2, bp1);
    k_sent<<<2048, 256, 0, stream>>>(y);

    k_persist<<<128, 512, 0, stream>>>(X, H1in, C1in, H2in, C2in, y,
                                       H1t, C1t, H2t, C2t,
                                       pk2, pk1, bp2, bp1,
                                       W1f, W1i, W1o, W1c);

    k_ygemm2<<<1024, 256, 0, stream>>>(y, pkY, bout);
}

// Round 13
// 2109.432 us; speedup vs baseline: 2.3406x; 2.3406x over previous
//
#include <hip/hip_runtime.h>
#include <math.h>

static constexpr int V  = 1024;
static constexpr int NH = 256;
static constexpr int B  = 128;
static constexpr int T  = 512;
static constexpr size_t BV  = (size_t)B * V;
static constexpr size_t YSZ = (size_t)T * B * V;   // 67,108,864
static constexpr unsigned SENT = 0xFFC0DEADu;      // NaN payload; h in (-1,1) never equals it

typedef _Float16 h8 __attribute__((ext_vector_type(8)));
typedef _Float16 h4 __attribute__((ext_vector_type(4)));
typedef float f32x4 __attribute__((ext_vector_type(4)));

#define MFMA16(a, b, c) __builtin_amdgcn_mfma_f32_16x16x32_f16((a), (b), (c), 0, 0, 0)
#define MALL_LD(dst, src) asm volatile("global_load_dwordx4 %0, %1, off sc0 sc1" : "=v"(dst) : "v"(src))

__device__ __forceinline__ void mall_store(float* p, f32x4 v) {
    asm volatile("global_store_dwordx4 %0, %1, off sc0 sc1" :: "v"(p), "v"(v) : "memory");
}

__device__ __forceinline__ float fast_sigmoid(float x) {
    float a = fminf(-1.442695041f * x, 126.0f);
    return __builtin_amdgcn_rcpf(1.0f + __builtin_amdgcn_exp2f(a));
}

__device__ __forceinline__ int has_sent(f32x4 v) {
    return (__float_as_uint(v[0]) == SENT) | (__float_as_uint(v[1]) == SENT) |
           (__float_as_uint(v[2]) == SENT) | (__float_as_uint(v[3]) == SENT);
}

__device__ __forceinline__ void cvtv(f32x4 u, h4* hi4, h4* lo4) {
    h4 hi, lo;
    #pragma unroll
    for (int e = 0; e < 4; ++e) {
        _Float16 h = (_Float16)u[e];
        hi[e] = h; lo[e] = (_Float16)((u[e] - (float)h) * 2048.0f);
    }
    *hi4 = hi; *lo4 = lo;
}

__device__ __forceinline__ float sel4(f32x4 p, int i) {
    float r = p[0];
    r = (i == 1) ? p[1] : r;
    r = (i == 2) ? p[2] : r;
    r = (i == 3) ? p[3] : r;
    return r;
}
__device__ __forceinline__ float pick4(float a0, float a1, float a2, float a3, int i) {
    float r = a0;
    r = (i == 1) ? a1 : r;
    r = (i == 2) ? a2 : r;
    r = (i == 3) ? a3 : r;
    return r;
}

// Split-f16: x = hi + lo*2^-11, lo pre-scaled 2048. Dot = hi*hi + (hi*lo + lo*hi)*2^-11.
// d_out: y[T*B][V], tails H1,C1,H2,C2. Stash: h2(t)->y[t][0:256], h1(t)->y[t][256:512].
// Sync = data-as-flag (SENT) via 16B MALL (sc0 sc1) ops.
// k_persist: 128 blocks x 256 thr (4 waves). Block (mp,np): rows mp*16..+16, hidden
// np*16..+16 of BOTH cells. Each wave: 16 gate-cols FULL-K + in-wave shuffle-transpose
// combine (no pre[][], verified R9/R12). Double-buffered LDS; ONE barrier per step.
// All threads stage (h1 polled first, h2 second for slack), then all compute.

__global__ __launch_bounds__(256) void k_prep(
    const float* __restrict__ W1f, const float* __restrict__ W1i,
    const float* __restrict__ W1o, const float* __restrict__ W1c,
    const float* __restrict__ W2f, const float* __restrict__ W2i,
    const float* __restrict__ W2o, const float* __restrict__ W2c,
    const float* __restrict__ Wout,
    const float* __restrict__ b1f, const float* __restrict__ b1i,
    const float* __restrict__ b1o, const float* __restrict__ b1c,
    const float* __restrict__ b2f, const float* __restrict__ b2i,
    const float* __restrict__ b2o, const float* __restrict__ b2c,
    _Float16* __restrict__ pk2, _Float16* __restrict__ pk1,
    _Float16* __restrict__ pkY, float* __restrict__ bp2, float* __restrict__ bp1)
{
    int idx = blockIdx.x * 256 + threadIdx.x;
    if (idx < 2097152) {
        int KB, e, rowoff = 0;
        bool vocabN = false;
        _Float16* dst;
        if (idx < 1048576)      { e = idx;            KB = 16; dst = pk2; }
        else if (idx < 1572864) { e = idx - 1048576;  KB = 8;  dst = pk1; rowoff = V; }
        else                    { e = idx - 1572864;  KB = 8;  dst = pkY; vocabN = true; }
        int S = 64 * KB * 512;
        int split = e / S, r = e % S;
        int grp = r / (KB * 512);
        int r2  = r % (KB * 512);
        int kb = r2 >> 9, lane = (r2 >> 3) & 63, i = r2 & 7;
        int n = grp * 16 + (lane & 15);
        int k = kb * 32 + (lane >> 4) * 8 + i;
        float val;
        if (vocabN) {
            val = Wout[(size_t)k * 1024 + n];
        } else {
            int j = n >> 2, g = n & 3;
            const float* W = (KB == 16)
                ? (g == 0 ? W2f : g == 1 ? W2i : g == 2 ? W2o : W2c)
                : (g == 0 ? W1f : g == 1 ? W1i : g == 2 ? W1o : W1c);
            val = W[(size_t)(rowoff + k) * NH + j];
        }
        _Float16 hi = (_Float16)val;
        dst[e] = split ? (_Float16)((val - (float)hi) * 2048.0f) : hi;
    } else {
        int bi = idx - 2097152;
        if (bi < 1024) {
            int j = bi >> 2, g = bi & 3;
            bp2[bi] = (g == 0 ? b2f : g == 1 ? b2i : g == 2 ? b2o : b2c)[j];
        } else if (bi < 2048) {
            int b2_ = bi - 1024;
            int j = b2_ >> 2, g = b2_ & 3;
            bp1[b2_] = (g == 0 ? b1f : g == 1 ? b1i : g == 2 ? b1o : b1c)[j];
        }
    }
}

__global__ __launch_bounds__(256) void k_sent(float* __restrict__ y) {
    const float s = __uint_as_float(SENT);
    const f32x4 sv = {s, s, s, s};
    int gid = blockIdx.x * 256 + threadIdx.x;       // 524288 threads
    for (int n = gid; n < 8388608; n += 524288) {
        int row = n >> 7, c4 = n & 127;
        *(f32x4*)&y[(size_t)row * V + c4 * 4] = sv;
    }
}

__global__ __launch_bounds__(256, 1) void k_persist(
    const int* __restrict__ X,
    const float* __restrict__ H1in, const float* __restrict__ C1in,
    const float* __restrict__ H2in, const float* __restrict__ C2in,
    float* __restrict__ y,
    float* __restrict__ H1t, float* __restrict__ C1t,
    float* __restrict__ H2t, float* __restrict__ C2t,
    const _Float16* __restrict__ pk2, const _Float16* __restrict__ pk1,
    const float* __restrict__ bp2, const float* __restrict__ bp1,
    const float* __restrict__ W1f, const float* __restrict__ W1i,
    const float* __restrict__ W1o, const float* __restrict__ W1c)
{
    const int bid = blockIdx.x, tid = threadIdx.x;
    const int mp = bid >> 4, np = bid & 15, r0 = mp * 16;

    __shared__ _Float16 Ah[2][16][520];
    __shared__ _Float16 Al[2][16][520];

    const int wq = tid >> 6, lane = tid & 63;
    const int col = lane & 15, kg = lane >> 4;
    const int c3 = lane & 3;
    const int orow = ((lane >> 4) << 2) | c3;
    const int jq = (lane >> 2) & 3;
    const int jglob = np * 16 + wq * 4 + jq;
    const int brow = r0 + orow;
    const int sk4 = tid & 63;      // staging col4 within 256-col half
    const int srb = tid >> 6;      // staging rows srb, +4, +8, +12

    // ---- full-K weights per thread: cell1 8+8 h8 (64 VGPR), cell2 16+16 (128) ----
    h8 wh1[8], wl1[8], wh2[16], wl2[16];
    {
        const _Float16* pB1 = pk1 + ((size_t)((np * 4 + wq) * 8) * 64 + lane) * 8;
        #pragma unroll
        for (int kb = 0; kb < 8; ++kb) {
            wh1[kb] = *(const h8*)(pB1 + (size_t)kb * 512);
            wl1[kb] = *(const h8*)(pB1 + 262144 + (size_t)kb * 512);
        }
        const _Float16* pB2 = pk2 + ((size_t)((np * 4 + wq) * 16) * 64 + lane) * 8;
        #pragma unroll
        for (int kb = 0; kb < 16; ++kb) {
            wh2[kb] = *(const h8*)(pB2 + (size_t)kb * 512);
            wl2[kb] = *(const h8*)(pB2 + 524288 + (size_t)kb * 512);
        }
    }
    float creg1 = C1in[brow * NH + jglob];
    float creg2 = C2in[brow * NH + jglob];
    const f32x4 bb1 = *(const f32x4*)&bp1[jglob * 4];
    const f32x4 bb2 = *(const f32x4*)&bp2[jglob * 4];
    float* const hst1 = y + (size_t)brow * V + 256 + np * 16 + wq * 4;
    float* const hst2 = y + (size_t)brow * V + np * 16 + wq * 4;

    // ================= prologue: cell1(0) from H1in (buf 1) =================
    #pragma unroll
    for (int g = 0; g < 4; ++g) {
        const int row = srb + g * 4;
        f32x4 u = *(const f32x4*)(H1in + (size_t)(r0 + row) * NH + sk4 * 4);
        cvtv(u, (h4*)&Ah[1][row][sk4 * 4], (h4*)&Al[1][row][sk4 * 4]);
    }
    __syncthreads();
    {
        int tok = X[brow * T + 0];
        float w1f_ = W1f[(size_t)tok * NH + jglob];
        float w1i_ = W1i[(size_t)tok * NH + jglob];
        float w1o_ = W1o[(size_t)tok * NH + jglob];
        float w1c_ = W1c[(size_t)tok * NH + jglob];
        f32x4 a0 = {0.f, 0.f, 0.f, 0.f}, a1 = a0, a2 = a0;
        #pragma unroll
        for (int kb = 0; kb < 8; ++kb) {
            h8 ah = *(const h8*)&Ah[1][col][kb * 32 + kg * 8];
            h8 al = *(const h8*)&Al[1][col][kb * 32 + kg * 8];
            a0 = MFMA16(ah, wh1[kb], a0);
            a1 = MFMA16(ah, wl1[kb], a1);
            a2 = MFMA16(al, wh1[kb], a2);
        }
        f32x4 comb = a0 + (a1 + a2) * (1.0f / 2048.0f);
        float s0 = sel4(comb, c3);
        float s1 = __shfl_xor(sel4(comb, c3 ^ 1), 1);
        float s2 = __shfl_xor(sel4(comb, c3 ^ 2), 2);
        float s3 = __shfl_xor(sel4(comb, c3 ^ 3), 3);
        float pf = pick4(s0, s1, s2, s3, c3)     + bb1[0] + w1f_;
        float pi = pick4(s0, s1, s2, s3, c3 ^ 1) + bb1[1] + w1i_;
        float po = pick4(s0, s1, s2, s3, c3 ^ 2) + bb1[2] + w1o_;
        float pc = pick4(s0, s1, s2, s3, c3 ^ 3) + bb1[3] + w1c_;
        float fg = fast_sigmoid(pf), ig = fast_sigmoid(pi), og = fast_sigmoid(po);
        creg1 = fmaf(fg, creg1, ig * tanhf(pc));
        float h = og * tanhf(creg1);
        float g1 = __shfl(h, (lane & 51) | 4);
        float g2 = __shfl(h, (lane & 51) | 8);
        float g3 = __shfl(h, (lane & 51) | 12);
        if ((lane & 12) == 0) {
            f32x4 hv = {h, g1, g2, g3};
            mall_store(hst1, hv);   // h1(0)
        }
    }

    // ================= main loop: ONE barrier per iter =================
    for (int t = 0; t < T; ++t) {
        const int tb = t & 1;
        // ---- poll h1(t) (produced early in producers' prev iter) ----
        {
            f32x4 u0, u1, u2, u3;
            const float* q0 = y + (size_t)t * BV + (size_t)(r0 + srb)      * V + 256 + sk4 * 4;
            const float* q1 = y + (size_t)t * BV + (size_t)(r0 + srb + 4)  * V + 256 + sk4 * 4;
            const float* q2 = y + (size_t)t * BV + (size_t)(r0 + srb + 8)  * V + 256 + sk4 * 4;
            const float* q3 = y + (size_t)t * BV + (size_t)(r0 + srb + 12) * V + 256 + sk4 * 4;
            MALL_LD(u0, q0); MALL_LD(u1, q1); MALL_LD(u2, q2); MALL_LD(u3, q3);
            asm volatile("s_waitcnt vmcnt(0)" : "+v"(u0), "+v"(u1), "+v"(u2), "+v"(u3));
            while (__any(has_sent(u0) | has_sent(u1) | has_sent(u2) | has_sent(u3))) {
                __builtin_amdgcn_s_sleep(1);
                MALL_LD(u0, q0); MALL_LD(u1, q1); MALL_LD(u2, q2); MALL_LD(u3, q3);
                asm volatile("s_waitcnt vmcnt(0)" : "+v"(u0), "+v"(u1), "+v"(u2), "+v"(u3));
            }
            cvtv(u0, (h4*)&Ah[tb][srb][sk4 * 4],      (h4*)&Al[tb][srb][sk4 * 4]);
            cvtv(u1, (h4*)&Ah[tb][srb + 4][sk4 * 4],  (h4*)&Al[tb][srb + 4][sk4 * 4]);
            cvtv(u2, (h4*)&Ah[tb][srb + 8][sk4 * 4],  (h4*)&Al[tb][srb + 8][sk4 * 4]);
            cvtv(u3, (h4*)&Ah[tb][srb + 12][sk4 * 4], (h4*)&Al[tb][srb + 12][sk4 * 4]);
        }
        // ---- poll h2(t-1) (second: gains the h1-poll time as slack) ----
        {
            f32x4 u0, u1, u2, u3;
            if (t) {
                const float* q0 = y + (size_t)(t - 1) * BV + (size_t)(r0 + srb)      * V + sk4 * 4;
                const float* q1 = y + (size_t)(t - 1) * BV + (size_t)(r0 + srb + 4)  * V + sk4 * 4;
                const float* q2 = y + (size_t)(t - 1) * BV + (size_t)(r0 + srb + 8)  * V + sk4 * 4;
                const float* q3 = y + (size_t)(t - 1) * BV + (size_t)(r0 + srb + 12) * V + sk4 * 4;
                MALL_LD(u0, q0); MALL_LD(u1, q1); MALL_LD(u2, q2); MALL_LD(u3, q3);
                asm volatile("s_waitcnt vmcnt(0)" : "+v"(u0), "+v"(u1), "+v"(u2), "+v"(u3));
                while (__any(has_sent(u0) | has_sent(u1) | has_sent(u2) | has_sent(u3))) {
                    __builtin_amdgcn_s_sleep(1);
                    MALL_LD(u0, q0); MALL_LD(u1, q1); MALL_LD(u2, q2); MALL_LD(u3, q3);
                    asm volatile("s_waitcnt vmcnt(0)" : "+v"(u0), "+v"(u1), "+v"(u2), "+v"(u3));
                }
            } else {
                u0 = *(const f32x4*)(H2in + (size_t)(r0 + srb)      * NH + sk4 * 4);
                u1 = *(const f32x4*)(H2in + (size_t)(r0 + srb + 4)  * NH + sk4 * 4);
                u2 = *(const f32x4*)(H2in + (size_t)(r0 + srb + 8)  * NH + sk4 * 4);
                u3 = *(const f32x4*)(H2in + (size_t)(r0 + srb + 12) * NH + sk4 * 4);
            }
            cvtv(u0, (h4*)&Ah[tb][srb][256 + sk4 * 4],      (h4*)&Al[tb][srb][256 + sk4 * 4]);
            cvtv(u1, (h4*)&Ah[tb][srb + 4][256 + sk4 * 4],  (h4*)&Al[tb][srb + 4][256 + sk4 * 4]);
            cvtv(u2, (h4*)&Ah[tb][srb + 8][256 + sk4 * 4],  (h4*)&Al[tb][srb + 8][256 + sk4 * 4]);
            cvtv(u3, (h4*)&Ah[tb][srb + 12][256 + sk4 * 4], (h4*)&Al[tb][srb + 12][256 + sk4 * 4]);
        }
        __syncthreads();   // the ONLY barrier per step

        // ---- cell1(t+1): critical chain first ----
        if (t <= 510) {
            int tok = X[brow * T + t + 1];
            float w1f_ = W1f[(size_t)tok * NH + jglob];
            float w1i_ = W1i[(size_t)tok * NH + jglob];
            float w1o_ = W1o[(size_t)tok * NH + jglob];
            float w1c_ = W1c[(size_t)tok * NH + jglob];
            f32x4 a0 = {0.f, 0.f, 0.f, 0.f}, a1 = a0, a2 = a0;
            #pragma unroll
            for (int kb = 0; kb < 8; ++kb) {
                h8 ah = *(const h8*)&Ah[tb][col][kb * 32 + kg * 8];
                h8 al = *(const h8*)&Al[tb][col][kb * 32 + kg * 8];
                a0 = MFMA16(ah, wh1[kb], a0);
                a1 = MFMA16(ah, wl1[kb], a1);
                a2 = MFMA16(al, wh1[kb], a2);
            }
            f32x4 comb = a0 + (a1 + a2) * (1.0f / 2048.0f);
            float s0 = sel4(comb, c3);
            float s1 = __shfl_xor(sel4(comb, c3 ^ 1), 1);
            float s2 = __shfl_xor(sel4(comb, c3 ^ 2), 2);
            float s3 = __shfl_xor(sel4(comb, c3 ^ 3), 3);
            float pf = pick4(s0, s1, s2, s3, c3)     + bb1[0] + w1f_;
            float pi = pick4(s0, s1, s2, s3, c3 ^ 1) + bb1[1] + w1i_;
            float po = pick4(s0, s1, s2, s3, c3 ^ 2) + bb1[2] + w1o_;
            float pc = pick4(s0, s1, s2, s3, c3 ^ 3) + bb1[3] + w1c_;
            float fg = fast_sigmoid(pf), ig = fast_sigmoid(pi), og = fast_sigmoid(po);
            creg1 = fmaf(fg, creg1, ig * tanhf(pc));
            float h = og * tanhf(creg1);
            float g1 = __shfl(h, (lane & 51) | 4);
            float g2 = __shfl(h, (lane & 51) | 8);
            float g3 = __shfl(h, (lane & 51) | 12);
            if ((lane & 12) == 0) {
                f32x4 hv = {h, g1, g2, g3};
                mall_store(hst1 + (size_t)(t + 1) * BV, hv);
            }
            if (t == 510) { H1t[brow * NH + jglob] = h; C1t[brow * NH + jglob] = creg1; }
        }
        // ---- cell2(t) ----
        {
            f32x4 a0 = {0.f, 0.f, 0.f, 0.f}, a1 = a0, a2 = a0;
            #pragma unroll
            for (int kb = 0; kb < 16; ++kb) {
                h8 ah = *(const h8*)&Ah[tb][col][kb * 32 + kg * 8];
                h8 al = *(const h8*)&Al[tb][col][kb * 32 + kg * 8];
                a0 = MFMA16(ah, wh2[kb], a0);
                a1 = MFMA16(ah, wl2[kb], a1);
                a2 = MFMA16(al, wh2[kb], a2);
            }
            f32x4 comb = a0 + (a1 + a2) * (1.0f / 2048.0f);
            float s0 = sel4(comb, c3);
            float s1 = __shfl_xor(sel4(comb, c3 ^ 1), 1);
            float s2 = __shfl_xor(sel4(comb, c3 ^ 2), 2);
            float s3 = __shfl_xor(sel4(comb, c3 ^ 3), 3);
            float pf = pick4(s0, s1, s2, s3, c3)     + bb2[0];
            float pi = pick4(s0, s1, s2, s3, c3 ^ 1) + bb2[1];
            float po = pick4(s0, s1, s2, s3, c3 ^ 2) + bb2[2];
            float pc = pick4(s0, s1, s2, s3, c3 ^ 3) + bb2[3];
            float fg = fast_sigmoid(pf), ig = fast_sigmoid(pi), og = fast_sigmoid(po);
            creg2 = fmaf(fg, creg2, ig * tanhf(pc));
            float h = og * tanhf(creg2);
            float g1 = __shfl(h, (lane & 51) | 4);
            float g2 = __shfl(h, (lane & 51) | 8);
            float g3 = __shfl(h, (lane & 51) | 12);
            if ((lane & 12) == 0) {
                f32x4 hv = {h, g1, g2, g3};
                mall_store(hst2 + (size_t)t * BV, hv);
            }
            if (t == 511) { H2t[brow * NH + jglob] = h; C2t[brow * NH + jglob] = creg2; }
        }
    }
}

// Y = H2_all @ Wout + bout, in place (block stages its 64 rows before writing).
__global__ __launch_bounds__(256) void k_ygemm2(
    float* __restrict__ y, const _Float16* __restrict__ pkY,
    const float* __restrict__ bout)
{
    __shared__ _Float16 Ah[64][264];
    __shared__ _Float16 Al[64][264];
    const size_t m0 = (size_t)blockIdx.x * 64;
    const int tid = threadIdx.x;
    for (int idx = tid; idx < 64 * 256; idx += 256) {
        int r = idx >> 8, k = idx & 255;
        float v = y[(m0 + r) * 1024 + k];
        _Float16 hi = (_Float16)v;
        Ah[r][k] = hi;
        Al[r][k] = (_Float16)((v - (float)hi) * 2048.0f);
    }
    __syncthreads();
    const int wave = tid >> 6, lane = tid & 63;
    const int col = lane & 15, kg = lane >> 4;
    const int ar = wave * 16 + col;
    const size_t orow = m0 + wave * 16 + kg * 4;
    for (int npass = 0; npass < 8; ++npass) {
        f32x4 aA[8], aB[8];
        #pragma unroll
        for (int nt = 0; nt < 8; ++nt) { aA[nt] = (f32x4){0.f,0.f,0.f,0.f}; aB[nt] = aA[nt]; }
        for (int kb = 0; kb < 8; ++kb) {
            h8 ah = *(const h8*)&Ah[ar][kb * 32 + kg * 8];
            h8 al = *(const h8*)&Al[ar][kb * 32 + kg * 8];
            #pragma unroll
            for (int nt = 0; nt < 8; ++nt) {
                const int ngrp = npass * 8 + nt;
                const _Float16* pb = pkY + ((size_t)(ngrp * 8 + kb) * 64 + lane) * 8;
                h8 bh = *(const h8*)pb;
                h8 bl = *(const h8*)(pb + 262144);
                aA[nt] = MFMA16(ah, bh, aA[nt]);
                aB[nt] = MFMA16(ah, bl, aB[nt]);
                aB[nt] = MFMA16(al, bh, aB[nt]);
            }
        }
        #pragma unroll
        for (int nt = 0; nt < 8; ++nt) {
            int n = npass * 128 + nt * 16 + col;
            float bbo = bout[n];
            #pragma unroll
            for (int q = 0; q < 4; ++q)
                y[(orow + q) * 1024 + n] = aA[nt][q] + aB[nt][q] * (1.0f / 2048.0f) + bbo;
        }
    }
}

// ---------------- launch ----------------
extern "C" void kernel_launch(void* const* d_in, const int* in_sizes, int n_in,
                              void* d_out, int out_size, void* d_ws, size_t ws_size,
                              hipStream_t stream) {
    const int*   X    = (const int*)  d_in[0];
    const float* H1in = (const float*)d_in[1];
    const float* C1in = (const float*)d_in[2];
    const float* H2in = (const float*)d_in[3];
    const float* C2in = (const float*)d_in[4];
    const float* W1f = (const float*)d_in[5];  const float* b1f = (const float*)d_in[6];
    const float* W1i = (const float*)d_in[7];  const float* b1i = (const float*)d_in[8];
    const float* W1o = (const float*)d_in[9];  const float* b1o = (const float*)d_in[10];
    const float* W1c = (const float*)d_in[11]; const float* b1c = (const float*)d_in[12];
    const float* W2f = (const float*)d_in[13]; const float* b2f = (const float*)d_in[14];
    const float* W2i = (const float*)d_in[15]; const float* b2i = (const float*)d_in[16];
    const float* W2o = (const float*)d_in[17]; const float* b2o = (const float*)d_in[18];
    const float* W2c = (const float*)d_in[19]; const float* b2c = (const float*)d_in[20];
    const float* Wout = (const float*)d_in[21]; const float* bout = (const float*)d_in[22];

    float* y   = (float*)d_out;
    float* H1t = y + YSZ;
    float* C1t = y + YSZ + 1 * 32768;
    float* H2t = y + YSZ + 2 * 32768;
    float* C2t = y + YSZ + 3 * 32768;

    char* ws = (char*)d_ws;
    _Float16* pk2 = (_Float16*)ws;
    _Float16* pk1 = pk2 + 1048576;
    _Float16* pkY = pk1 + 524288;
    float* bp2 = (float*)(ws + 4194304);
    float* bp1 = bp2 + 1024;

    k_prep<<<8200, 256, 0, stream>>>(W1f, W1i, W1o, W1c, W2f, W2i, W2o, W2c, Wout,
                                     b1f, b1i, b1o, b1c, b2f, b2i, b2o, b2c,
                                     pk2, pk1, pkY, bp2, bp1);
    k_sent<<<2048, 256, 0, stream>>>(y);

    k_persist<<<128, 256, 0, stream>>>(X, H1in, C1in, H2in, C2in, y,
                                       H1t, C1t, H2t, C2t,
                                       pk2, pk1, bp2, bp1,
                                       W1f, W1i, W1o, W1c);

    k_ygemm2<<<1024, 256, 0, stream>>>(y, pkY, bout);
}